// Round 1
// baseline (856.984 us; speedup 1.0000x reference)
//
#include <hip/hip_runtime.h>

#define B_ 64
#define T_ 2048
#define LD_ 16
#define HD_ 64
#define K_ 8

// ---------------- workspace layout (floats) ----------------
constexpr int OFF_EH    = 0;                        // (T+1)*B*K  (1 pad row for prefetch clamp)
constexpr int OFF_M     = (T_+1)*B_*K_;             // (T+1)*B
constexpr int OFF_ALPHA = OFF_M + (T_+1)*B_;        // T*B*K
constexpr int OFF_EBAR  = OFF_ALPHA + T_*B_*K_;     // T*B*K
constexpr int OFF_B     = OFF_EBAR + T_*B_*K_;      // T*B*K
constexpr int OFF_PRM   = OFF_B + T_*B_*K_;

// params region (relative to OFF_PRM)
constexpr int P_LINV0 = 0;       // 8*16*16
constexpr int P_LD0   = 2048;    // 8
constexpr int P_LINVT = 2056;    // 8*16*16
constexpr int P_LDT   = 4104;    // 8
constexpr int P_LOGPI = 4112;    // 8
constexpr int P_QEXP  = 4120;    // 64  exp(log_softmax(Q,rows))
constexpr int P_QTEXP = 4184;    // 64  transpose of above

// output layout (floats)
constexpr int OUT_PAIRED = B_*T_*K_;                         // 1048576
constexpr int OUT_LOGZ   = OUT_PAIRED + B_*(T_-1)*K_*K_;     // 9433088

// ---------------- DPP helpers (groups of 8 lanes) ----------------
template<int CTRL>
__device__ __forceinline__ float dppmov(float x) {
  int xi = __float_as_int(x);
  int r = __builtin_amdgcn_update_dpp(xi, xi, CTRL, 0xF, 0xF, true);
  return __int_as_float(r);
}
// quad_perm [1,0,3,2] = xor1 : 0xB1 ; quad_perm [2,3,0,1] = xor2 : 0x4E
// row_half_mirror = xor7 within 8 lanes : 0x141
__device__ __forceinline__ void allg8(float v, float w[8]) {
  w[0] = v;
  w[1] = dppmov<0xB1>(v);     // v[i^1]
  w[2] = dppmov<0x4E>(v);     // v[i^2]
  w[3] = dppmov<0x4E>(w[1]);  // v[i^3]
  w[7] = dppmov<0x141>(v);    // v[i^7]
  w[6] = dppmov<0xB1>(w[7]);  // v[i^6]
  w[5] = dppmov<0x4E>(w[7]);  // v[i^5]
  w[4] = dppmov<0x4E>(w[6]);  // v[i^4]
}

// ---------------- kernel 1: Cholesky / softmax params ----------------
__global__ __launch_bounds__(64) void prep_kernel(
    const float* __restrict__ pi, const float* __restrict__ Q,
    const float* __restrict__ init_cov, const float* __restrict__ covs,
    float* __restrict__ prm)
{
  int tid = threadIdx.x;
  int blk = blockIdx.x;
  if (blk < 16) {
    int k = blk & 7;
    const float* C = (blk < 8 ? init_cov : covs) + k*256;
    float* outL  = prm + (blk < 8 ? P_LINV0 : P_LINVT) + k*256;
    float* outld = prm + (blk < 8 ? P_LD0   : P_LDT)   + k;
    __shared__ float S[16][17], L[16][17], X[16][17];
    // Sigma = C C^T + 1e-6 I
    for (int e = tid; e < 256; e += 64) {
      int r = e >> 4, c = e & 15;
      float s = (r == c) ? 1e-6f : 0.f;
      for (int l = 0; l < 16; l++) s += C[r*16+l] * C[c*16+l];
      S[r][c] = s;
    }
    __syncthreads();
    // right-looking Cholesky
    for (int j = 0; j < 16; j++) {
      if (tid == 0) L[j][j] = sqrtf(S[j][j]);
      __syncthreads();
      if (tid > j && tid < 16) L[tid][j] = S[tid][j] / L[j][j];
      __syncthreads();
      if (tid > j && tid < 16) {
        float ltj = L[tid][j];
        for (int c = j+1; c <= tid; c++) S[tid][c] -= ltj * L[c][j];
      }
      __syncthreads();
    }
    // forward substitution: L X = I, column per thread
    if (tid < 16) {
      int c = tid;
      for (int r = 0; r < 16; r++) {
        float v;
        if (r < c) v = 0.f;
        else {
          v = (r == c) ? 1.f : 0.f;
          for (int s2 = c; s2 < r; s2++) v -= L[r][s2] * X[s2][c];
          v /= L[r][r];
        }
        X[r][c] = v;
      }
    }
    __syncthreads();
    for (int e = tid; e < 256; e += 64) outL[e] = X[e>>4][e&15];
    if (tid == 0) {
      float ld = 0.f;
      for (int j = 0; j < 16; j++) ld += logf(L[j][j]);
      *outld = ld;
    }
  } else {
    if (tid < 8) {        // row `tid` of Qlog
      int row = tid;
      float q[8], mx = -1e30f;
      for (int j = 0; j < 8; j++) { q[j] = Q[row*8+j]; mx = fmaxf(mx, q[j]); }
      float s = 0.f;
      for (int j = 0; j < 8; j++) s += __expf(q[j]-mx);
      float ls = logf(s);
      for (int j = 0; j < 8; j++) {
        float e = __expf(q[j]-mx-ls);
        prm[P_QEXP  + row*8 + j] = e;
        prm[P_QTEXP + j*8 + row] = e;
      }
    } else if (tid == 8) { // log_softmax(pi)
      float p[8], mx = -1e30f;
      for (int j = 0; j < 8; j++) { p[j] = pi[j]; mx = fmaxf(mx, p[j]); }
      float s = 0.f;
      for (int j = 0; j < 8; j++) s += __expf(p[j]-mx);
      float ls = logf(s);
      for (int j = 0; j < 8; j++) prm[P_LOGPI+j] = p[j]-mx-ls;
    }
  }
}

// ---------------- kernel 2: emissions -> ehat, m ----------------
// thread = (t,b) with tid = t*64 + b : each wave has one t (no divergence),
// weight reads are wave-uniform (scalar-cache friendly)
__global__ __launch_bounds__(256) void emis_kernel(
    const float* __restrict__ z, const float* __restrict__ W1,
    const float* __restrict__ b1, const float* __restrict__ W2,
    const float* __restrict__ b2, const float* __restrict__ init_mean,
    const float* __restrict__ prm, float* __restrict__ eh, float* __restrict__ mbuf)
{
  int tid = blockIdx.x*256 + threadIdx.x;
  int t = tid >> 6, b = tid & 63;
  float zc[16];
  const float* zcp = z + (b*T_ + t)*LD_;
  #pragma unroll
  for (int l = 0; l < 16; l++) zc[l] = zcp[l];
  float le[8];
  if (t == 0) {
    #pragma unroll
    for (int k = 0; k < 8; k++) {
      float diff[16];
      #pragma unroll
      for (int l = 0; l < 16; l++) diff[l] = zc[l] - init_mean[k*16+l];
      const float* Li = prm + P_LINV0 + k*256;
      float maha = 0.f;
      #pragma unroll
      for (int d = 0; d < 16; d++) {
        float y = 0.f;
        #pragma unroll
        for (int e = 0; e < 16; e++) y += Li[d*16+e] * diff[e];
        maha += y*y;
      }
      le[k] = -0.5f*maha - prm[P_LD0+k] - 14.70301653f + prm[P_LOGPI+k];
    }
  } else {
    float zp[16];
    const float* zpp = z + (b*T_ + t - 1)*LD_;
    #pragma unroll
    for (int l = 0; l < 16; l++) zp[l] = zpp[l];
    for (int k = 0; k < 8; k++) {
      float h[64];
      #pragma unroll
      for (int hh = 0; hh < 64; hh++) {
        float a = b1[k*64+hh];
        #pragma unroll
        for (int l = 0; l < 16; l++) a += W1[k*1024 + hh*16 + l] * zp[l];
        // softplus = max(a,0) + log1p(exp(-|a|))
        h[hh] = fmaxf(a, 0.f) + __logf(1.f + __expf(-fabsf(a)));
      }
      float diff[16];
      #pragma unroll
      for (int d = 0; d < 16; d++) {
        float mu = b2[k*16+d];
        #pragma unroll
        for (int hh = 0; hh < 64; hh++) mu += W2[k*1024 + d*64 + hh] * h[hh];
        diff[d] = zc[d] - mu;
      }
      const float* Li = prm + P_LINVT + k*256;
      float maha = 0.f;
      #pragma unroll
      for (int d = 0; d < 16; d++) {
        float y = 0.f;
        #pragma unroll
        for (int e = 0; e < 16; e++) y += Li[d*16+e] * diff[e];
        maha += y*y;
      }
      le[k] = -0.5f*maha - prm[P_LDT+k] - 14.70301653f;
    }
  }
  float m = le[0];
  #pragma unroll
  for (int k = 1; k < 8; k++) m = fmaxf(m, le[k]);
  mbuf[t*64 + b] = m;
  #pragma unroll
  for (int k = 0; k < 8; k++) eh[t*512 + b*8 + k] = __expf(le[k]-m);
}

// ---------------- kernel 3: forward scan (rescaled linear space) ------------
// 8 blocks x 64 threads; lane = (batch_sub<<3) | state i. v_t = c~_t * alpha_t.
__global__ __launch_bounds__(64) void fwd_kernel(
    const float* __restrict__ eh, const float* __restrict__ mbuf,
    const float* __restrict__ prm, float* __restrict__ alpha,
    float* __restrict__ ebar, float* __restrict__ out)
{
  int lane = threadIdx.x;
  int i = lane & 7;
  int b = blockIdx.x*8 + (lane >> 3);
  float* logZ = out + OUT_LOGZ + b*T_;
  int off = b*8 + i;
  float q[8];
  #pragma unroll
  for (int k = 0; k < 8; k++) q[k] = prm[P_QTEXP + i*8 + (i^k)];
  float e_prev = eh[off];          // ehat_0[i] (logpi already folded in)
  float v_prev = e_prev;           // v_0
  float m_prev = mbuf[b];
  float ec[8], mc[8];
  #pragma unroll
  for (int u = 0; u < 8; u++) { ec[u] = eh[(1+u)*512 + off]; mc[u] = mbuf[(1+u)*64 + b]; }
  for (int tb = 1; tb < 2048; tb += 8) {
    float en[8], mn[8];
    #pragma unroll
    for (int u = 0; u < 8; u++) {          // prefetch next chunk (clamped to pad row)
      int t2 = tb + 8 + u; t2 = (t2 > 2048) ? 2048 : t2;
      en[u] = eh[t2*512 + off]; mn[u] = mbuf[t2*64 + b];
    }
    #pragma unroll
    for (int u = 0; u < 8; u++) {
      int t = tb + u;                      // t = 1..2048 ; iteration 2048 only stores for 2047
      float w[8]; allg8(v_prev, w);
      float cp = ((w[0]+w[1])+(w[2]+w[3])) + ((w[4]+w[5])+(w[6]+w[7]));   // c_{t-1}
      float r0 = __builtin_amdgcn_rcpf(cp);
      float r  = r0 * __builtin_fmaf(-cp, r0, 2.0f);                      // 1/c_{t-1}
      float dotv = (q[0]*w[0]+q[1]*w[1]) + (q[2]*w[2]+q[3]*w[3])
                 + (q[4]*w[4]+q[5]*w[5]) + (q[6]*w[6]+q[7]*w[7]);         // (Q^T v)_i
      float v = dotv * ec[u] * r;                                         // v_t
      alpha[(t-1)*512 + off] = v_prev * r;                                // alpha_{t-1}
      ebar [(t-1)*512 + off] = e_prev * r;                                // ehat/c
      logZ[t-1] = m_prev + __logf(cp);                                    // lz_{t-1}
      v_prev = v; e_prev = ec[u]; m_prev = mc[u];
    }
    #pragma unroll
    for (int u = 0; u < 8; u++) { ec[u] = en[u]; mc[u] = mn[u]; }
  }
}

// ---------------- kernel 4: backward scan ----------------
__global__ __launch_bounds__(64) void bwd_kernel(
    const float* __restrict__ ebar, const float* __restrict__ prm,
    float* __restrict__ bbuf)
{
  int lane = threadIdx.x;
  int i = lane & 7;
  int b = blockIdx.x*8 + (lane >> 3);
  int off = b*8 + i;
  float q[8];
  #pragma unroll
  for (int k = 0; k < 8; k++) q[k] = prm[P_QEXP + i*8 + (i^k)];
  float bb = 1.0f;
  bbuf[2047*512 + off] = 1.0f;
  float ec[8];
  #pragma unroll
  for (int u = 0; u < 8; u++) ec[u] = ebar[(2047-u)*512 + off];
  for (int tb = 2046; tb >= 6; tb -= 8) {
    float en[8];
    #pragma unroll
    for (int u = 0; u < 8; u++) { int t2 = tb-7-u; t2 = (t2 < 0) ? 0 : t2; en[u] = ebar[t2*512 + off]; }
    #pragma unroll
    for (int u = 0; u < 8; u++) {
      int t = tb - u;                      // down to -1 in the last chunk (store guarded)
      float wv = ec[u] * bb;               // ebar_{t+1}[i] * b_{t+1}[i]
      float w[8]; allg8(wv, w);
      bb = (q[0]*w[0]+q[1]*w[1]) + (q[2]*w[2]+q[3]*w[3])
         + (q[4]*w[4]+q[5]*w[5]) + (q[6]*w[6]+q[7]*w[7]);
      if (t >= 0) bbuf[t*512 + off] = bb;
    }
    #pragma unroll
    for (int u = 0; u < 8; u++) ec[u] = en[u];
  }
}

// ---------------- kernel 5: gamma & paired ----------------
__global__ __launch_bounds__(256) void post_kernel(
    const float* __restrict__ alpha, const float* __restrict__ ebar,
    const float* __restrict__ bbuf, const float* __restrict__ prm,
    float* __restrict__ out)
{
  int tid = blockIdx.x*256 + threadIdx.x;
  int wid = tid >> 6;
  int lane = tid & 63;
  int b = wid >> 11, t = wid & 2047;
  int i = lane >> 3, j = lane & 7;
  if (lane < 8) {
    float ag = alpha[t*512 + b*8 + lane];
    float bg = bbuf [t*512 + b*8 + lane];
    out[b*(T_*K_) + t*8 + lane] = ag * bg;            // gamma
  }
  if (t < 2047) {
    float a  = alpha[t*512 + b*8 + i];
    float qe = prm[P_QEXP + lane];
    float eb = ebar[(t+1)*512 + b*8 + j];
    float bv = bbuf[(t+1)*512 + b*8 + j];
    out[OUT_PAIRED + b*((T_-1)*64) + t*64 + lane] = a * qe * eb * bv;   // paired
  }
}

extern "C" void kernel_launch(void* const* d_in, const int* in_sizes, int n_in,
                              void* d_out, int out_size, void* d_ws, size_t ws_size,
                              hipStream_t stream) {
  const float* z         = (const float*)d_in[0];
  const float* pi        = (const float*)d_in[1];
  const float* Q         = (const float*)d_in[2];
  const float* init_mean = (const float*)d_in[3];
  const float* init_cov  = (const float*)d_in[4];
  const float* covs      = (const float*)d_in[5];
  const float* W1        = (const float*)d_in[6];
  const float* b1        = (const float*)d_in[7];
  const float* W2        = (const float*)d_in[8];
  const float* b2        = (const float*)d_in[9];
  float* out = (float*)d_out;
  float* ws  = (float*)d_ws;

  prep_kernel<<<17, 64, 0, stream>>>(pi, Q, init_cov, covs, ws + OFF_PRM);
  emis_kernel<<<(B_*T_)/256, 256, 0, stream>>>(z, W1, b1, W2, b2, init_mean,
                                               ws + OFF_PRM, ws + OFF_EH, ws + OFF_M);
  fwd_kernel<<<8, 64, 0, stream>>>(ws + OFF_EH, ws + OFF_M, ws + OFF_PRM,
                                   ws + OFF_ALPHA, ws + OFF_EBAR, out);
  bwd_kernel<<<8, 64, 0, stream>>>(ws + OFF_EBAR, ws + OFF_PRM, ws + OFF_B);
  post_kernel<<<(B_*T_*64)/256, 256, 0, stream>>>(ws + OFF_ALPHA, ws + OFF_EBAR,
                                                  ws + OFF_B, ws + OFF_PRM, out);
}

// Round 2
// 516.182 us; speedup vs baseline: 1.6602x; 1.6602x over previous
//
#include <hip/hip_runtime.h>

#define B_ 64
#define T_ 2048
#define LD_ 16
#define HD_ 64
#define K_ 8
#define L_ 32
#define C_ 64

// ---------------- workspace layout (floats) ----------------
constexpr int OFF_LE    = 0;                   // T*B*K  (aliased with bbuf: le dead after emisB)
constexpr int OFF_BB    = 0;                   // bbuf (written by bwdP3, long after le is dead)
constexpr int OFF_EH    = 1048576;             // T*B*K   ehat
constexpr int OFF_M     = OFF_EH + 1048576;    // T*B     per-(t,b) max
constexpr int OFF_ALPHA = OFF_M  + 131072;     // T*B*K
constexpr int OFF_EBAR  = OFF_ALPHA + 1048576; // T*B*K
constexpr int OFF_PBUF  = OFF_EBAR  + 1048576; // C*B*64 = 262144 (fwd P; aliased w/ bwd R)
constexpr int OFF_RLOG  = OFF_PBUF + 262144;   // C*B = 4096
constexpr int OFF_AIN   = OFF_RLOG + 4096;     // C*B*K = 32768
constexpr int OFF_BENT  = OFF_AIN  + 32768;    // C*B*K = 32768
constexpr int OFF_PRM   = OFF_BENT + 32768;

// params region (relative to OFF_PRM)
constexpr int P_LINV0 = 0;       // 8*16*16
constexpr int P_LD0   = 2048;    // 8
constexpr int P_LINVT = 2056;    // 8*16*16
constexpr int P_LDT   = 4104;    // 8
constexpr int P_LOGPI = 4112;    // 8
constexpr int P_QEXP  = 4120;    // 64  exp(log_softmax(Q,rows))
constexpr int P_QTEXP = 4184;    // 64  transpose of above

// output layout (floats)
constexpr int OUT_PAIRED = B_*T_*K_;                         // 1048576
constexpr int OUT_LOGZ   = OUT_PAIRED + B_*(T_-1)*K_*K_;     // 9433088

// ---------------- DPP helpers (groups of 8 lanes) ----------------
template<int CTRL>
__device__ __forceinline__ float dppmov(float x) {
  int xi = __float_as_int(x);
  int r = __builtin_amdgcn_update_dpp(xi, xi, CTRL, 0xF, 0xF, true);
  return __int_as_float(r);
}
// quad_perm [1,0,3,2]=xor1 : 0xB1 ; quad_perm [2,3,0,1]=xor2 : 0x4E ; row_half_mirror=xor7 : 0x141
// allg8: w[u] = v[lane ^ u] within aligned groups of 8 lanes
__device__ __forceinline__ void allg8(float v, float w[8]) {
  w[0] = v;
  w[1] = dppmov<0xB1>(v);
  w[2] = dppmov<0x4E>(v);
  w[3] = dppmov<0x4E>(w[1]);
  w[7] = dppmov<0x141>(v);
  w[6] = dppmov<0xB1>(w[7]);
  w[5] = dppmov<0x4E>(w[7]);
  w[4] = dppmov<0x4E>(w[6]);
}
__device__ __forceinline__ float bfly_sum8(float x) {
  x += dppmov<0xB1>(x); x += dppmov<0x4E>(x); x += dppmov<0x141>(x); return x;
}
__device__ __forceinline__ float bfly_max8(float x) {
  x = fmaxf(x, dppmov<0xB1>(x)); x = fmaxf(x, dppmov<0x4E>(x)); x = fmaxf(x, dppmov<0x141>(x)); return x;
}
__device__ __forceinline__ float rcpnr(float x) {
  float r0 = __builtin_amdgcn_rcpf(x);
  return r0 * __builtin_fmaf(-x, r0, 2.0f);
}

// ---------------- kernel 1: Cholesky / softmax params ----------------
__global__ __launch_bounds__(64) void prep_kernel(
    const float* __restrict__ pi, const float* __restrict__ Q,
    const float* __restrict__ init_cov, const float* __restrict__ covs,
    float* __restrict__ prm)
{
  int tid = threadIdx.x;
  int blk = blockIdx.x;
  if (blk < 16) {
    int k = blk & 7;
    const float* C = (blk < 8 ? init_cov : covs) + k*256;
    float* outL  = prm + (blk < 8 ? P_LINV0 : P_LINVT) + k*256;
    float* outld = prm + (blk < 8 ? P_LD0   : P_LDT)   + k;
    __shared__ float S[16][17], L[16][17], X[16][17];
    for (int e = tid; e < 256; e += 64) {
      int r = e >> 4, c = e & 15;
      float s = (r == c) ? 1e-6f : 0.f;
      for (int l = 0; l < 16; l++) s += C[r*16+l] * C[c*16+l];
      S[r][c] = s;
    }
    __syncthreads();
    for (int j = 0; j < 16; j++) {
      if (tid == 0) L[j][j] = sqrtf(S[j][j]);
      __syncthreads();
      if (tid > j && tid < 16) L[tid][j] = S[tid][j] / L[j][j];
      __syncthreads();
      if (tid > j && tid < 16) {
        float ltj = L[tid][j];
        for (int c = j+1; c <= tid; c++) S[tid][c] -= ltj * L[c][j];
      }
      __syncthreads();
    }
    if (tid < 16) {
      int c = tid;
      for (int r = 0; r < 16; r++) {
        float v;
        if (r < c) v = 0.f;
        else {
          v = (r == c) ? 1.f : 0.f;
          for (int s2 = c; s2 < r; s2++) v -= L[r][s2] * X[s2][c];
          v /= L[r][r];
        }
        X[r][c] = v;
      }
    }
    __syncthreads();
    for (int e = tid; e < 256; e += 64) outL[e] = X[e>>4][e&15];
    if (tid == 0) {
      float ld = 0.f;
      for (int j = 0; j < 16; j++) ld += logf(L[j][j]);
      *outld = ld;
    }
  } else {
    if (tid < 8) {
      int row = tid;
      float q[8], mx = -1e30f;
      for (int j = 0; j < 8; j++) { q[j] = Q[row*8+j]; mx = fmaxf(mx, q[j]); }
      float s = 0.f;
      for (int j = 0; j < 8; j++) s += __expf(q[j]-mx);
      float ls = logf(s);
      for (int j = 0; j < 8; j++) {
        float e = __expf(q[j]-mx-ls);
        prm[P_QEXP  + row*8 + j] = e;
        prm[P_QTEXP + j*8 + row] = e;
      }
    } else if (tid == 8) {
      float p[8], mx = -1e30f;
      for (int j = 0; j < 8; j++) { p[j] = pi[j]; mx = fmaxf(mx, p[j]); }
      float s = 0.f;
      for (int j = 0; j < 8; j++) s += __expf(p[j]-mx);
      float ls = logf(s);
      for (int j = 0; j < 8; j++) prm[P_LOGPI+j] = p[j]-mx-ls;
    }
  }
}

// ---------------- kernel 2a: emissions, wave=(k,t), lane=b ----------------
__global__ __launch_bounds__(256) void emisA_kernel(
    const float* __restrict__ z, const float* __restrict__ W1,
    const float* __restrict__ b1, const float* __restrict__ W2,
    const float* __restrict__ b2, const float* __restrict__ init_mean,
    const float* __restrict__ prm, float* __restrict__ lebuf)
{
  int b = threadIdx.x & 63;
  int wid = __builtin_amdgcn_readfirstlane(blockIdx.x * 4 + (threadIdx.x >> 6));
  int k = wid >> 11;          // wave-uniform (SGPR)
  int t = wid & 2047;         // wave-uniform (SGPR)
  float zc[16];
  {
    const float4* p4 = (const float4*)(z + (b*T_ + t)*LD_);
    float4 v0=p4[0], v1=p4[1], v2=p4[2], v3=p4[3];
    zc[0]=v0.x; zc[1]=v0.y; zc[2]=v0.z; zc[3]=v0.w;
    zc[4]=v1.x; zc[5]=v1.y; zc[6]=v1.z; zc[7]=v1.w;
    zc[8]=v2.x; zc[9]=v2.y; zc[10]=v2.z; zc[11]=v2.w;
    zc[12]=v3.x; zc[13]=v3.y; zc[14]=v3.z; zc[15]=v3.w;
  }
  float le;
  if (t == 0) {
    float diff[16];
    #pragma unroll
    for (int l = 0; l < 16; l++) diff[l] = zc[l] - init_mean[k*16+l];
    const float* Li = prm + P_LINV0 + k*256;
    float maha = 0.f;
    #pragma unroll
    for (int d = 0; d < 16; d++) {
      float y = 0.f;
      #pragma unroll
      for (int e = 0; e < 16; e++) y = __builtin_fmaf(Li[d*16+e], diff[e], y);
      maha = __builtin_fmaf(y, y, maha);
    }
    le = -0.5f*maha - prm[P_LD0+k] - 14.70301653f + prm[P_LOGPI+k];
  } else {
    float zp[16];
    {
      const float4* p4 = (const float4*)(z + (b*T_ + t - 1)*LD_);
      float4 v0=p4[0], v1=p4[1], v2=p4[2], v3=p4[3];
      zp[0]=v0.x; zp[1]=v0.y; zp[2]=v0.z; zp[3]=v0.w;
      zp[4]=v1.x; zp[5]=v1.y; zp[6]=v1.z; zp[7]=v1.w;
      zp[8]=v2.x; zp[9]=v2.y; zp[10]=v2.z; zp[11]=v2.w;
      zp[12]=v3.x; zp[13]=v3.y; zp[14]=v3.z; zp[15]=v3.w;
    }
    float h[64];
    #pragma unroll
    for (int hh = 0; hh < 64; hh++) {
      float a = b1[k*64+hh];
      #pragma unroll
      for (int l = 0; l < 16; l++) a = __builtin_fmaf(W1[k*1024 + hh*16 + l], zp[l], a);
      h[hh] = fmaxf(a, 0.f) + __logf(1.f + __expf(-fabsf(a)));
    }
    float diff[16];
    #pragma unroll
    for (int d = 0; d < 16; d++) {
      float mu = b2[k*16+d];
      #pragma unroll
      for (int hh = 0; hh < 64; hh++) mu = __builtin_fmaf(W2[k*1024 + d*64 + hh], h[hh], mu);
      diff[d] = zc[d] - mu;
    }
    const float* Li = prm + P_LINVT + k*256;
    float maha = 0.f;
    #pragma unroll
    for (int d = 0; d < 16; d++) {
      float y = 0.f;
      #pragma unroll
      for (int e = 0; e < 16; e++) y = __builtin_fmaf(Li[d*16+e], diff[e], y);
      maha = __builtin_fmaf(y, y, maha);
    }
    le = -0.5f*maha - prm[P_LDT+k] - 14.70301653f;
  }
  lebuf[t*512 + k*64 + b] = le;   // coalesced per wave
}

// ---------------- kernel 2b: m = max_k le ; ehat = exp(le-m) ----------------
__global__ __launch_bounds__(256) void emisB_kernel(
    const float* __restrict__ lebuf, float* __restrict__ eh, float* __restrict__ mbuf)
{
  int tid = blockIdx.x*256 + threadIdx.x;   // 131072 = T*B
  int t = tid >> 6, b = tid & 63;
  float le[8];
  #pragma unroll
  for (int k = 0; k < 8; k++) le[k] = lebuf[t*512 + k*64 + b];
  float m = le[0];
  #pragma unroll
  for (int k = 1; k < 8; k++) m = fmaxf(m, le[k]);
  mbuf[t*64 + b] = m;
  float4 o0, o1;
  o0.x = __expf(le[0]-m); o0.y = __expf(le[1]-m); o0.z = __expf(le[2]-m); o0.w = __expf(le[3]-m);
  o1.x = __expf(le[4]-m); o1.y = __expf(le[5]-m); o1.z = __expf(le[6]-m); o1.w = __expf(le[7]-m);
  float4* dst = (float4*)(eh + t*512 + b*8);
  dst[0] = o0; dst[1] = o1;
}

// ---------------- fwd phase 1: per-(b,chunk) operator products ----------------
// group of 8 lanes = (b,c); lane j holds column j of P in xor-permuted layout:
// pl[u] = P[j^u][j].  P_c = prod_{t in chunk} diag(ehat_t) Q^T, max-normalized.
__global__ __launch_bounds__(256) void fwdP1_kernel(
    const float* __restrict__ eh, const float* __restrict__ prm, float* __restrict__ pbuf)
{
  int g = (blockIdx.x*256 + threadIdx.x) >> 3;   // 0..4095
  int j = threadIdx.x & 7;
  int b = g & 63, c = g >> 6;                    // c uniform per block
  float qtv[64];                                  // qtv[u*8+v] = QT[j^u][j^v]
  #pragma unroll
  for (int u = 0; u < 8; u++)
    #pragma unroll
    for (int v = 0; v < 8; v++)
      qtv[u*8+v] = prm[P_QTEXP + (j^u)*8 + (j^v)];
  float ev[32];
  #pragma unroll
  for (int u = 0; u < 32; u++) ev[u] = eh[(c*L_+u)*512 + b*8 + j];
  float pl[8];
  int ustart;
  if (c == 0) {
    float e8[8]; allg8(ev[0], e8);
    #pragma unroll
    for (int u = 0; u < 8; u++) pl[u] = e8[u];   // P[:,j] = ehat_0 (all columns equal)
    ustart = 1;
  } else {
    #pragma unroll
    for (int u = 0; u < 8; u++) pl[u] = (u == 0) ? 1.f : 0.f;  // identity
    ustart = 0;
  }
  for (int s = ustart; s < 32; s++) {
    float e8[8]; allg8(ev[s], e8);
    float np[8];
    #pragma unroll
    for (int u = 0; u < 8; u++) {
      float acc = 0.f;
      #pragma unroll
      for (int v = 0; v < 8; v++) acc = __builtin_fmaf(qtv[u*8+v], pl[v], acc);
      np[u] = e8[u] * acc;
    }
    float mx = np[0];
    #pragma unroll
    for (int u = 1; u < 8; u++) mx = fmaxf(mx, np[u]);
    mx = bfly_max8(mx);
    float r = rcpnr(mx);     // common scale -> columns stay mutually consistent
    #pragma unroll
    for (int u = 0; u < 8; u++) pl[u] = np[u] * r;
  }
  float4* dst = (float4*)(pbuf + g*64 + j*8);
  dst[0] = make_float4(pl[0], pl[1], pl[2], pl[3]);
  dst[1] = make_float4(pl[4], pl[5], pl[6], pl[7]);
}

// ---------------- fwd phase 2: serial chunk-boundary recursion ----------------
// 512 lanes: (b,i).  ain[c] = alpha_{c*L-1} for c=1..63.
__global__ __launch_bounds__(512) void fwdP2_kernel(
    const float* __restrict__ pbuf, float* __restrict__ ain)
{
  int lane = threadIdx.x;
  int b = lane >> 3, i = lane & 7;
  float a = 0.125f;                 // chunk 0's columns are all equal -> dummy works
  float rw[8];
  #pragma unroll
  for (int u = 0; u < 8; u++) rw[u] = pbuf[(0*64+b)*64 + (i^u)*8 + u];  // P[i][i^u]
  for (int c = 0; c < 63; c++) {
    float nx[8];
    #pragma unroll
    for (int u = 0; u < 8; u++) nx[u] = pbuf[((c+1)*64+b)*64 + (i^u)*8 + u];
    float aw[8]; allg8(a, aw);      // aw[u] = a[i^u]
    float s = 0.f;
    #pragma unroll
    for (int u = 0; u < 8; u++) s = __builtin_fmaf(rw[u], aw[u], s);
    float tot = bfly_sum8(s);
    a = s * rcpnr(tot);
    ain[(c+1)*512 + b*8 + i] = a;
    #pragma unroll
    for (int u = 0; u < 8; u++) rw[u] = nx[u];
  }
}

// ---------------- fwd phase 3: within-chunk rerun, emit alpha/ebar/logZ -------
__global__ __launch_bounds__(256) void fwdP3_kernel(
    const float* __restrict__ eh, const float* __restrict__ mbuf,
    const float* __restrict__ prm, const float* __restrict__ ain,
    float* __restrict__ alpha, float* __restrict__ ebar, float* __restrict__ out)
{
  int g = (blockIdx.x*256 + threadIdx.x) >> 3;
  int i = threadIdx.x & 7;
  int b = g & 63, c = g >> 6;
  int off = b*8 + i;
  float q[8];
  #pragma unroll
  for (int u = 0; u < 8; u++) q[u] = prm[P_QTEXP + i*8 + (i^u)];
  float ev[32], mv[32];
  #pragma unroll
  for (int u = 0; u < 32; u++) ev[u] = eh[(c*L_+u)*512 + off];
  #pragma unroll
  for (int u = 0; u < 32; u++) mv[u] = mbuf[(c*L_+u)*64 + b];
  float* logZ = out + OUT_LOGZ + b*T_;
  float a;
  int ustart;
  if (c == 0) {
    float ct = bfly_sum8(ev[0]);
    float r = rcpnr(ct);
    a = ev[0] * r;
    alpha[off] = a;
    ebar [off] = a;
    if (i == 0) logZ[0] = mv[0] + __logf(ct);
    ustart = 1;
  } else {
    a = ain[c*512 + off];
    ustart = 0;
  }
  for (int u = ustart; u < 32; u++) {
    int t = c*L_ + u;
    float w[8]; allg8(a, w);        // w[u2] = a[i^u2]
    float dot = ((q[0]*w[0]+q[1]*w[1]) + (q[2]*w[2]+q[3]*w[3]))
              + ((q[4]*w[4]+q[5]*w[5]) + (q[6]*w[6]+q[7]*w[7]));   // (Q^T a)_i
    float p = ev[u] * dot;
    float ct = bfly_sum8(p);
    float r = rcpnr(ct);
    a = p * r;
    alpha[t*512 + off] = a;
    ebar [t*512 + off] = ev[u] * r;
    if (i == 0) logZ[t] = mv[u] + __logf(ct);
  }
}

// ---------------- bwd phase 1: R_c = prod M_t (decreasing t), log-scaled ------
// rl[u] = R[j^u][j];  R <- Q diag(ebar_{t+1}) R,  t+1 = c*L+u, u = 31..0
__global__ __launch_bounds__(256) void bwdP1_kernel(
    const float* __restrict__ ebar, const float* __restrict__ prm,
    float* __restrict__ rbuf, float* __restrict__ rlog)
{
  int g = (blockIdx.x*256 + threadIdx.x) >> 3;
  int j = threadIdx.x & 7;
  int b = g & 63, c = g >> 6;
  float qv[64];                                   // qv[u*8+v] = Q[j^u][j^v]
  #pragma unroll
  for (int u = 0; u < 8; u++)
    #pragma unroll
    for (int v = 0; v < 8; v++)
      qv[u*8+v] = prm[P_QEXP + (j^u)*8 + (j^v)];
  float ev[32];
  #pragma unroll
  for (int u = 0; u < 32; u++) ev[u] = ebar[(c*L_+u)*512 + b*8 + j];
  float rl[8];
  #pragma unroll
  for (int u = 0; u < 8; u++) rl[u] = (u == 0) ? 1.f : 0.f;
  float lsc = 0.f;
  for (int s = 31; s >= 0; s--) {
    float e8[8]; allg8(ev[s], e8);                // e8[v] = ebar[j^v]
    float nr[8];
    #pragma unroll
    for (int u = 0; u < 8; u++) {
      float acc = 0.f;
      #pragma unroll
      for (int v = 0; v < 8; v++) acc = __builtin_fmaf(qv[u*8+v], e8[v]*rl[v], acc);
      nr[u] = acc;
    }
    float mx = nr[0];
    #pragma unroll
    for (int u = 1; u < 8; u++) mx = fmaxf(mx, nr[u]);
    mx = bfly_max8(mx);
    float r = rcpnr(mx);
    #pragma unroll
    for (int u = 0; u < 8; u++) rl[u] = nr[u] * r;
    lsc += __logf(mx);
  }
  float4* dst = (float4*)(rbuf + g*64 + j*8);
  dst[0] = make_float4(rl[0], rl[1], rl[2], rl[3]);
  dst[1] = make_float4(rl[4], rl[5], rl[6], rl[7]);
  if (j == 0) rlog[g] = lsc;
}

// ---------------- bwd phase 2: serial boundary recursion (log-scaled) ---------
// bent[c] = beta at t=(c+1)*L-1 (actual values; |log| bounded for valid data)
__global__ __launch_bounds__(512) void bwdP2_kernel(
    const float* __restrict__ rbuf, const float* __restrict__ rlog,
    float* __restrict__ bent)
{
  int lane = threadIdx.x;
  int b = lane >> 3, i = lane & 7;
  bent[63*512 + b*8 + i] = 1.f;
  float sh = 1.f, sig = 0.f;        // true beta = sh * exp(sig)
  float rw[8];
  #pragma unroll
  for (int u = 0; u < 8; u++) rw[u] = rbuf[(63*64+b)*64 + (i^u)*8 + u];
  for (int c = 63; c >= 1; c--) {
    float nx[8];
    int cp = (c > 1) ? (c-1) : 1;
    #pragma unroll
    for (int u = 0; u < 8; u++) nx[u] = rbuf[(cp*64+b)*64 + (i^u)*8 + u];
    float sw[8]; allg8(sh, sw);
    float y = 0.f;
    #pragma unroll
    for (int u = 0; u < 8; u++) y = __builtin_fmaf(rw[u], sw[u], y);
    float mx = bfly_max8(y);
    sh = y * rcpnr(mx);
    sig += rlog[c*64 + b] + __logf(mx);
    bent[(c-1)*512 + b*8 + i] = sh * __expf(sig);
    #pragma unroll
    for (int u = 0; u < 8; u++) rw[u] = nx[u];
  }
}

// ---------------- bwd phase 3: within-chunk rerun, emit beta -----------------
__global__ __launch_bounds__(256) void bwdP3_kernel(
    const float* __restrict__ ebar, const float* __restrict__ prm,
    const float* __restrict__ bent, float* __restrict__ bbuf)
{
  int g = (blockIdx.x*256 + threadIdx.x) >> 3;
  int i = threadIdx.x & 7;
  int b = g & 63, c = g >> 6;
  int off = b*8 + i;
  float q[8];
  #pragma unroll
  for (int u = 0; u < 8; u++) q[u] = prm[P_QEXP + i*8 + (i^u)];
  float ev[32];
  #pragma unroll
  for (int u = 1; u < 32; u++) ev[u] = ebar[(c*L_+u)*512 + off];
  float bb = bent[c*512 + off];
  bbuf[(c*L_+31)*512 + off] = bb;
  for (int u = 31; u >= 1; u--) {     // t = c*L+u-1 uses ebar_{t+1}=ev[u]
    float wv = ev[u] * bb;
    float w[8]; allg8(wv, w);         // w[u2] = (ebar*b)[i^u2]
    bb = ((q[0]*w[0]+q[1]*w[1]) + (q[2]*w[2]+q[3]*w[3]))
       + ((q[4]*w[4]+q[5]*w[5]) + (q[6]*w[6]+q[7]*w[7]));
    bbuf[(c*L_+u-1)*512 + off] = bb;
  }
}

// ---------------- gamma & paired ----------------
__global__ __launch_bounds__(256) void post_kernel(
    const float* __restrict__ alpha, const float* __restrict__ ebar,
    const float* __restrict__ bbuf, const float* __restrict__ prm,
    float* __restrict__ out)
{
  int tid = blockIdx.x*256 + threadIdx.x;
  int wid = tid >> 6;
  int lane = tid & 63;
  int b = wid >> 11, t = wid & 2047;
  int i = lane >> 3, j = lane & 7;
  if (lane < 8) {
    float ag = alpha[t*512 + b*8 + lane];
    float bg = bbuf [t*512 + b*8 + lane];
    out[b*(T_*K_) + t*8 + lane] = ag * bg;            // gamma
  }
  if (t < 2047) {
    float a  = alpha[t*512 + b*8 + i];
    float qe = prm[P_QEXP + lane];
    float eb = ebar[(t+1)*512 + b*8 + j];
    float bv = bbuf[(t+1)*512 + b*8 + j];
    out[OUT_PAIRED + b*((T_-1)*64) + t*64 + lane] = a * qe * eb * bv;   // paired
  }
}

extern "C" void kernel_launch(void* const* d_in, const int* in_sizes, int n_in,
                              void* d_out, int out_size, void* d_ws, size_t ws_size,
                              hipStream_t stream) {
  const float* z         = (const float*)d_in[0];
  const float* pi        = (const float*)d_in[1];
  const float* Q         = (const float*)d_in[2];
  const float* init_mean = (const float*)d_in[3];
  const float* init_cov  = (const float*)d_in[4];
  const float* covs      = (const float*)d_in[5];
  const float* W1        = (const float*)d_in[6];
  const float* b1        = (const float*)d_in[7];
  const float* W2        = (const float*)d_in[8];
  const float* b2        = (const float*)d_in[9];
  float* out = (float*)d_out;
  float* ws  = (float*)d_ws;

  prep_kernel<<<17, 64, 0, stream>>>(pi, Q, init_cov, covs, ws + OFF_PRM);
  emisA_kernel<<<4096, 256, 0, stream>>>(z, W1, b1, W2, b2, init_mean,
                                         ws + OFF_PRM, ws + OFF_LE);
  emisB_kernel<<<512, 256, 0, stream>>>(ws + OFF_LE, ws + OFF_EH, ws + OFF_M);
  fwdP1_kernel<<<128, 256, 0, stream>>>(ws + OFF_EH, ws + OFF_PRM, ws + OFF_PBUF);
  fwdP2_kernel<<<1, 512, 0, stream>>>(ws + OFF_PBUF, ws + OFF_AIN);
  fwdP3_kernel<<<128, 256, 0, stream>>>(ws + OFF_EH, ws + OFF_M, ws + OFF_PRM,
                                        ws + OFF_AIN, ws + OFF_ALPHA, ws + OFF_EBAR, out);
  bwdP1_kernel<<<128, 256, 0, stream>>>(ws + OFF_EBAR, ws + OFF_PRM,
                                        ws + OFF_PBUF, ws + OFF_RLOG);
  bwdP2_kernel<<<1, 512, 0, stream>>>(ws + OFF_PBUF, ws + OFF_RLOG, ws + OFF_BENT);
  bwdP3_kernel<<<128, 256, 0, stream>>>(ws + OFF_EBAR, ws + OFF_PRM,
                                        ws + OFF_BENT, ws + OFF_BB);
  post_kernel<<<32768, 256, 0, stream>>>(ws + OFF_ALPHA, ws + OFF_EBAR,
                                         ws + OFF_BB, ws + OFF_PRM, out);
}